// Round 4
// baseline (115.873 us; speedup 1.0000x reference)
//
#include <hip/hip_runtime.h>
#include <hip/hip_bf16.h>
#include <hip/hip_fp16.h>

#define PP 9216   // 96*96 pixels per batch
#define OO 384    // qkv channels

typedef _Float16 f16x8 __attribute__((ext_vector_type(8)));
typedef _Float16 h2    __attribute__((ext_vector_type(2)));
typedef float    f32x4 __attribute__((ext_vector_type(4)));

#if defined(__has_builtin)
# if __has_builtin(__builtin_amdgcn_fdot2)
#  define HAS_FDOT2 1
# endif
#endif

__device__ __forceinline__ float dot2acc(h2 a, h2 b, float c) {
#ifdef HAS_FDOT2
    return __builtin_amdgcn_fdot2(a, b, c, false);
#else
    return c + (float)a[0] * (float)b[0] + (float)a[1] * (float)b[1];
#endif
}

// ---------------------------------------------------------------------------
// Fused x-transpose + QKV GEMM.
// qkv[b][p][o] = sum_c x[b][c][p] * w[o][c]  (w = wq|wk|wv by o/128), f16 MFMA.
// Block: 64 px x 192 o. Wave: 32 px x 96 o. x tile staged f32 in LDS,
// A-frags via LDS transpose-read + cvt; weights cvt'd in-register from L2.
// LDS epilogue for coalesced 16B f16 stores.
// ---------------------------------------------------------------------------
__global__ __launch_bounds__(256) void qkv_fused(
    const float* __restrict__ x, const float* __restrict__ wq,
    const float* __restrict__ wk, const float* __restrict__ wv,
    _Float16* __restrict__ qkv)
{
    __shared__ float sX[128][68];   // 34.8 KB; epilogue aliases this

    const int b = blockIdx.z;
    const int p0 = blockIdx.x * 64;
    const int nbase = blockIdx.y * 192;
    const int t = threadIdx.x;
    const int w = t >> 6, lane = t & 63;
    const int lm = lane & 15, quad = lane >> 4;
    const int ms0 = (w & 1) * 32;
    const int nw = (w >> 1) * 96;

    const float* xb = x + (size_t)b * 128 * PP;
    _Float16* qb = qkv + (size_t)b * PP * OO;

    // stage x tile: 128 c x 64 px, f32, coalesced 16B loads
    #pragma unroll
    for (int i = 0; i < 8; i++) {
        int idx = t + 256 * i;          // 0..2047 float4s
        int c  = idx >> 4;
        int p4 = idx & 15;
        *(float4*)&sX[c][p4 * 4] = *(const float4*)(xb + (size_t)c * PP + p0 + p4 * 4);
    }
    __syncthreads();

    // A-frags: lane pixel = p0+ms0+ms*16+lm, 8 channels per kc chunk
    f16x8 A[2][4];
    #pragma unroll
    for (int ms = 0; ms < 2; ms++) {
        const int px = ms0 + ms * 16 + lm;
        #pragma unroll
        for (int kc = 0; kc < 4; kc++) {
            const int c0 = kc * 32 + quad * 8;
            f16x8 a;
            #pragma unroll
            for (int j = 0; j < 8; j++) a[j] = (_Float16)sX[c0 + j][px];
            A[ms][kc] = a;
        }
    }

    f32x4 acc[6][2];
    #pragma unroll
    for (int nt = 0; nt < 6; nt++) {
        const int o0 = nbase + nw + nt * 16 + lm;
        const float* wsrc = (o0 < 128) ? (wq + (size_t)o0 * 128)
                          : (o0 < 256) ? (wk + (size_t)(o0 - 128) * 128)
                                       : (wv + (size_t)(o0 - 256) * 128);
        f16x8 Bf[4];
        #pragma unroll
        for (int kc = 0; kc < 4; kc++) {
            float4 a0 = *(const float4*)(wsrc + kc * 32 + quad * 8);
            float4 a1 = *(const float4*)(wsrc + kc * 32 + quad * 8 + 4);
            Bf[kc] = (f16x8){(_Float16)a0.x, (_Float16)a0.y, (_Float16)a0.z, (_Float16)a0.w,
                             (_Float16)a1.x, (_Float16)a1.y, (_Float16)a1.z, (_Float16)a1.w};
        }
        #pragma unroll
        for (int ms = 0; ms < 2; ms++) {
            acc[nt][ms] = (f32x4){0.f, 0.f, 0.f, 0.f};
            #pragma unroll
            for (int kc = 0; kc < 4; kc++)
                acc[nt][ms] = __builtin_amdgcn_mfma_f32_16x16x32_f16(A[ms][kc], Bf[kc], acc[nt][ms], 0, 0, 0);
        }
    }

    __syncthreads();   // all waves done reading sX; safe to alias for epilogue

    // per-wave epilogue strip: 32 px x 96 o, stride 104 halfs
    _Float16* sE = (_Float16*)&sX[0][0] + w * (32 * 104);
    #pragma unroll
    for (int nt = 0; nt < 6; nt++)
        #pragma unroll
        for (int ms = 0; ms < 2; ms++)
            #pragma unroll
            for (int r = 0; r < 4; r++)
                sE[(ms * 16 + quad * 4 + r) * 104 + nt * 16 + lm] = (_Float16)acc[nt][ms][r];

    // wave-private region: no barrier needed (compiler inserts lgkmcnt wait)
    #pragma unroll
    for (int it = 0; it < 6; it++) {
        int idx = it * 64 + lane;      // 0..383
        int row = idx / 12;            // 0..31
        int ch  = idx % 12;            // 16B chunk within 96-half row
        uint4 v = *(const uint4*)(sE + row * 104 + ch * 8);
        *(uint4*)(qb + (size_t)(p0 + ms0 + row) * OO + nbase + nw + ch * 8) = v;
    }
}

// ---------------------------------------------------------------------------
// Fused windowed attention + output projection, all heads in parallel.
// Block = 8-wide x 4-tall pixel tile, one batch. qkv[b][p][384] f16.
// K|V halo for ALL heads staged as contiguous 512B row copies.
// Scores: 256 thr = (32 px x 4 h x 2 pos-halves). Softmax: 128 rows.
// PV: 16 d per thread. Proj via MFMA -> out[b][c][p] f32.
// ---------------------------------------------------------------------------
__global__ __launch_bounds__(256) void attn_proj(
    const _Float16* __restrict__ qkv, const float* __restrict__ wp,
    float* __restrict__ out)
{
    __shared__ _Float16 sKV[96 * 264]; // halo 8 rows x 12 cols: k[0:128)|v[128:256), pad 8
    __shared__ float    sS[128 * 26];  // score rows r = h*32+px
    __shared__ _Float16 sAo[32 * 136]; // [px][128 o]

    const int t  = threadIdx.x;
    const int x0 = blockIdx.x * 8;
    const int y0 = blockIdx.y * 4;
    const int b  = blockIdx.z;
    const _Float16* base = qkv + (size_t)b * PP * OO;

    // stage K,V halo: 96 pos x 32 chunks of 16B, fully coalesced
    #pragma unroll
    for (int i = 0; i < 12; i++) {
        int idx = t + 256 * i;         // 0..3071
        int pos = idx >> 5;
        int ch  = idx & 31;
        int gy = y0 - 2 + pos / 12;
        int gx = x0 - 2 + pos % 12;
        uint4 v = {0u, 0u, 0u, 0u};
        if ((unsigned)gy < 96u && (unsigned)gx < 96u)
            v = *(const uint4*)(base + (size_t)(gy * 96 + gx) * OO + 128 + ch * 8);
        *(uint4*)(sKV + pos * 264 + ch * 8) = v;
    }

    const int px = t & 31, h = (t >> 5) & 3, pg = t >> 7;
    const int ly = px >> 3, lx = px & 7;
    const int gp0 = (y0 + ly) * 96 + x0 + lx;
    const int r = h * 32 + px;
    const float scale = 0.17677669529663689f; // 1/sqrt(32)

    // Q for (px,h) into registers (32 halfs)
    h2 qreg[16];
    {
        const _Float16* qs = base + (size_t)gp0 * OO + h * 32;
        #pragma unroll
        for (int j = 0; j < 4; j++)
            *(uint4*)(&qreg[j * 4]) = *(const uint4*)(qs + j * 8);
    }
    __syncthreads();

    // scores: this thread does pos in [pg?13:0, pg?25:13)
    {
        const int pbeg = pg ? 13 : 0, pend = pg ? 25 : 13;
        for (int pos = pbeg; pos < pend; pos++) {
            const int hp = (ly + pos / 5) * 12 + lx + pos % 5;
            const _Float16* kr = sKV + hp * 264 + h * 32;
            h2 kreg[16];
            #pragma unroll
            for (int j = 0; j < 4; j++)
                *(uint4*)(&kreg[j * 4]) = *(const uint4*)(kr + j * 8);
            float s0 = 0.f, s1 = 0.f;
            #pragma unroll
            for (int j = 0; j < 8; j++) {
                s0 = dot2acc(qreg[2 * j], kreg[2 * j], s0);
                s1 = dot2acc(qreg[2 * j + 1], kreg[2 * j + 1], s1);
            }
            sS[r * 26 + pos] = (s0 + s1) * scale;
        }
    }
    __syncthreads();

    // softmax over 25 positions, 128 rows in parallel
    if (t < 128) {
        float* row = sS + t * 26;
        float m = row[0];
        #pragma unroll
        for (int p = 1; p < 25; p++) m = fmaxf(m, row[p]);
        float sum = 0.f;
        float e[25];
        #pragma unroll
        for (int p = 0; p < 25; p++) { e[p] = __expf(row[p] - m); sum += e[p]; }
        const float inv = 1.f / sum;
        #pragma unroll
        for (int p = 0; p < 25; p++) row[p] = e[p] * inv;
    }
    __syncthreads();

    // PV: this thread does d in [pg*16, pg*16+16) for (px,h)
    {
        float at[25];
        #pragma unroll
        for (int p = 0; p < 25; p++) at[p] = sS[r * 26 + p];

        float f[16];
        #pragma unroll
        for (int j = 0; j < 16; j++) f[j] = 0.f;
        for (int p = 0; p < 25; p++) {
            const int hp = (ly + p / 5) * 12 + lx + p % 5;
            const _Float16* vr = sKV + hp * 264 + 128 + h * 32 + pg * 16;
            h2 vreg[8];
            *(uint4*)(&vreg[0]) = *(const uint4*)vr;
            *(uint4*)(&vreg[4]) = *(const uint4*)(vr + 8);
            #pragma unroll
            for (int j = 0; j < 8; j++) {
                f[2 * j]     += at[p] * (float)vreg[j][0];
                f[2 * j + 1] += at[p] * (float)vreg[j][1];
            }
        }
        _Float16 ho[16];
        #pragma unroll
        for (int j = 0; j < 16; j++) ho[j] = (_Float16)f[j];
        *(uint4*)(sAo + px * 136 + h * 32 + pg * 16)     = *(uint4*)(&ho[0]);
        *(uint4*)(sAo + px * 136 + h * 32 + pg * 16 + 8) = *(uint4*)(&ho[8]);
    }
    __syncthreads();

    // ---- projection: out[c][px] = sum_o wp[c][o] * ao[px][o] ----
    const int lane = t & 63, w4 = t >> 6;
    const int lm = lane & 15, quad = lane >> 4;

    f16x8 Aw[2][4];   // wproj rows c = w4*32 + mt*16 + lm
    #pragma unroll
    for (int mt = 0; mt < 2; mt++)
        #pragma unroll
        for (int kc = 0; kc < 4; kc++) {
            const float* ws_ = wp + (size_t)(w4 * 32 + mt * 16 + lm) * 128 + kc * 32 + quad * 8;
            float4 a0 = *(const float4*)ws_;
            float4 a1 = *(const float4*)(ws_ + 4);
            Aw[mt][kc] = (f16x8){(_Float16)a0.x, (_Float16)a0.y, (_Float16)a0.z, (_Float16)a0.w,
                                 (_Float16)a1.x, (_Float16)a1.y, (_Float16)a1.z, (_Float16)a1.w};
        }

    f32x4 acc[2][2];
    #pragma unroll
    for (int mt = 0; mt < 2; mt++)
        #pragma unroll
        for (int nt = 0; nt < 2; nt++)
            acc[mt][nt] = (f32x4){0.f, 0.f, 0.f, 0.f};

    #pragma unroll
    for (int nt = 0; nt < 2; nt++) {
        f16x8 Bf[4];
        #pragma unroll
        for (int kc = 0; kc < 4; kc++)
            Bf[kc] = *(const f16x8*)(sAo + (nt * 16 + lm) * 136 + kc * 32 + quad * 8);
        #pragma unroll
        for (int mt = 0; mt < 2; mt++)
            #pragma unroll
            for (int kc = 0; kc < 4; kc++)
                acc[mt][nt] = __builtin_amdgcn_mfma_f32_16x16x32_f16(Aw[mt][kc], Bf[kc], acc[mt][nt], 0, 0, 0);
    }

    float* ob = out + (size_t)b * 128 * PP;
    #pragma unroll
    for (int mt = 0; mt < 2; mt++)
        #pragma unroll
        for (int nt = 0; nt < 2; nt++) {
            const int pxl = nt * 16 + lm;
            const int gpl = (y0 + (pxl >> 3)) * 96 + x0 + (pxl & 7);
            #pragma unroll
            for (int rr = 0; rr < 4; rr++) {
                const int c = w4 * 32 + mt * 16 + quad * 4 + rr;
                ob[(size_t)c * PP + gpl] = acc[mt][nt][rr];
            }
        }
}

extern "C" void kernel_launch(void* const* d_in, const int* in_sizes, int n_in,
                              void* d_out, int out_size, void* d_ws, size_t ws_size,
                              hipStream_t stream)
{
    const float* x  = (const float*)d_in[0];
    const float* wq = (const float*)d_in[1];
    const float* wk = (const float*)d_in[2];
    const float* wv = (const float*)d_in[3];
    const float* wp = (const float*)d_in[4];
    float* out = (float*)d_out;

    _Float16* qkvh = (_Float16*)d_ws;   // 2*9216*384 f16 = 14.2 MB

    qkv_fused<<<dim3(144, 2, 2), 256, 0, stream>>>(x, wq, wk, wv, qkvh);
    attn_proj<<<dim3(12, 24, 2), 256, 0, stream>>>(qkvh, wp, out);
}

// Round 5
// 107.475 us; speedup vs baseline: 1.0781x; 1.0781x over previous
//
#include <hip/hip_runtime.h>
#include <hip/hip_bf16.h>
#include <hip/hip_fp16.h>

#define PP 9216   // 96*96 pixels per batch
#define OO 384    // qkv channels

typedef _Float16 f16x8 __attribute__((ext_vector_type(8)));
typedef _Float16 h2    __attribute__((ext_vector_type(2)));
typedef float    f32x4 __attribute__((ext_vector_type(4)));

#if defined(__has_builtin)
# if __has_builtin(__builtin_amdgcn_fdot2)
#  define HAS_FDOT2 1
# endif
#endif

__device__ __forceinline__ float dot2acc(h2 a, h2 b, float c) {
#ifdef HAS_FDOT2
    return __builtin_amdgcn_fdot2(a, b, c, false);
#else
    return c + (float)a[0] * (float)b[0] + (float)a[1] * (float)b[1];
#endif
}

// ---------------------------------------------------------------------------
// prep: (y<4) transpose x[b][c][p] f32 -> xT[b][p][c] f16 in 32x32 tiles;
//       (y==4,z==0) convert weights to f16 (wq|wk|wv concat rows, wproj).
// ---------------------------------------------------------------------------
__global__ __launch_bounds__(256) void prep(
    const float* __restrict__ x, const float* __restrict__ wq,
    const float* __restrict__ wk, const float* __restrict__ wv,
    const float* __restrict__ wp,
    _Float16* __restrict__ xT, _Float16* __restrict__ wqkv,
    _Float16* __restrict__ wproj)
{
    const int t = threadIdx.x;
    if (blockIdx.y == 4) {
        if (blockIdx.z) return;
        int idx = blockIdx.x * 256 + t;
        if (idx < 49152) {
            int o = idx >> 7;
            const float* src = (o < 128) ? wq : ((o < 256) ? wk : wv);
            wqkv[idx] = (_Float16)src[(o & 127) * 128 + (idx & 127)];
        } else if (idx < 65536) {
            int j = idx - 49152;
            wproj[j] = (_Float16)wp[j];
        }
        return;
    }
    __shared__ float sT[32][33];
    const int p0 = blockIdx.x * 32;
    const int c0 = blockIdx.y * 32;
    const int b  = blockIdx.z;
    const int row = t >> 3, col = t & 7;

    const float* xb = x + (size_t)b * 128 * PP;
    float4 v = *(const float4*)(xb + (size_t)(c0 + row) * PP + p0 + col * 4);
    sT[col * 4 + 0][row] = v.x;
    sT[col * 4 + 1][row] = v.y;
    sT[col * 4 + 2][row] = v.z;
    sT[col * 4 + 3][row] = v.w;
    __syncthreads();

    _Float16 h[4];
    #pragma unroll
    for (int j = 0; j < 4; j++) h[j] = (_Float16)sT[row][col * 4 + j];
    *(ushort4*)(xT + (size_t)b * PP * 128 + (size_t)(p0 + row) * 128 + c0 + col * 4) =
        *(ushort4*)h;
}

// ---------------------------------------------------------------------------
// QKV GEMM: qkv[b][p][o] = sum_c xT[b][p][c] * wqkv[o][c], f16 MFMA, no LDS
// staging; LDS epilogue for coalesced 16B stores (192B runs per pixel row).
// Block: 64px x 192o. Wave: 32px x 96o.
// ---------------------------------------------------------------------------
__global__ __launch_bounds__(256) void qkv_gemm(
    const _Float16* __restrict__ xT, const _Float16* __restrict__ wqkv,
    _Float16* __restrict__ qkv)
{
    __shared__ _Float16 sEpi[4][32][104];   // per-wave 32px x 96o strip (pad 104)

    const int b = blockIdx.z;
    const int p0 = blockIdx.x * 64;
    const int nbase = blockIdx.y * 192;
    const int t = threadIdx.x;
    const int w = t >> 6, lane = t & 63;
    const int lm = lane & 15, quad = lane >> 4;
    const int ms0 = (w & 1) * 32;
    const int nw = (w >> 1) * 96;

    const _Float16* xb = xT + (size_t)b * PP * 128;
    _Float16* qb = qkv + (size_t)b * PP * OO;

    f16x8 A[2][4];
    #pragma unroll
    for (int ms = 0; ms < 2; ms++)
        #pragma unroll
        for (int kc = 0; kc < 4; kc++)
            A[ms][kc] = *(const f16x8*)(xb + (size_t)(p0 + ms0 + ms * 16 + lm) * 128
                                        + kc * 32 + quad * 8);

    for (int nt = 0; nt < 6; nt++) {
        const int n0 = nbase + nw + nt * 16;
        f16x8 Bf[4];
        #pragma unroll
        for (int kc = 0; kc < 4; kc++)
            Bf[kc] = *(const f16x8*)(wqkv + (size_t)(n0 + lm) * 128 + kc * 32 + quad * 8);
        f32x4 acc[2];
        #pragma unroll
        for (int ms = 0; ms < 2; ms++) {
            acc[ms] = (f32x4){0.f, 0.f, 0.f, 0.f};
            #pragma unroll
            for (int kc = 0; kc < 4; kc++)
                acc[ms] = __builtin_amdgcn_mfma_f32_16x16x32_f16(A[ms][kc], Bf[kc], acc[ms], 0, 0, 0);
        }
        #pragma unroll
        for (int ms = 0; ms < 2; ms++)
            #pragma unroll
            for (int r = 0; r < 4; r++)
                sEpi[w][ms * 16 + quad * 4 + r][nt * 16 + lm] = (_Float16)acc[ms][r];
    }

    // per-wave epilogue: 32 rows x 96 halfs (192B contiguous per row)
    #pragma unroll
    for (int it = 0; it < 6; it++) {
        int idx = it * 64 + lane;      // 0..383
        int row = idx / 12;            // 0..31
        int ch  = idx % 12;            // 16B chunk within row
        uint4 v = *(const uint4*)&sEpi[w][row][ch * 8];
        *(uint4*)(qb + (size_t)(p0 + ms0 + row) * OO + nbase + nw + ch * 8) = v;
    }
}

// ---------------------------------------------------------------------------
// Windowed attention. qkv[b][p][384] f16 (q:0-127,k:128-255,v:256-383,
// each h*32+d). One block per (8x8 tile, b, h). ao[b][p][128] f16.
// ---------------------------------------------------------------------------
__global__ __launch_bounds__(256) void attn2(
    const _Float16* __restrict__ qkv, _Float16* __restrict__ ao)
{
    __shared__ _Float16 sK[144 * 40];
    __shared__ _Float16 sV[144 * 40];
    __shared__ float sS[64 * 28];

    const int t = threadIdx.x;
    const int x0 = blockIdx.x * 8, y0 = blockIdx.y * 8;
    const int b = blockIdx.z >> 2, h = blockIdx.z & 3;
    const _Float16* base = qkv + (size_t)b * PP * OO;

    // stage K,V halo: 144 pos x 32 halfs each, contiguous 64B rows
    for (int u = t; u < 288; u += 256) {
        const int arr = (u >= 144) ? 1 : 0;
        const int pos = u - 144 * arr;
        const int gy = y0 - 2 + pos / 12;
        const int gx = x0 - 2 + pos % 12;
        _Float16* dst = (arr ? sV : sK) + pos * 40;
        if ((unsigned)gy < 96u && (unsigned)gx < 96u) {
            const _Float16* src = base + (size_t)(gy * 96 + gx) * OO + 128 + arr * 128 + h * 32;
            #pragma unroll
            for (int j = 0; j < 4; j++)
                *(uint4*)(dst + j * 8) = *(const uint4*)(src + j * 8);
        } else {
            uint4 z = {0u, 0u, 0u, 0u};
            #pragma unroll
            for (int j = 0; j < 4; j++) *(uint4*)(dst + j * 8) = z;
        }
    }

    const int px = t & 63, w = t >> 6;
    const int ly = px >> 3, lx = px & 7;
    const int gp = (y0 + ly) * 96 + x0 + lx;

    // Q into registers (16 x half2)
    h2 qreg[16];
    {
        const _Float16* qs = base + (size_t)gp * OO + h * 32;
        #pragma unroll
        for (int j = 0; j < 4; j++)
            *(uint4*)(&qreg[j * 4]) = *(const uint4*)(qs + j * 8);
    }
    __syncthreads();

    // scores: wave w handles pos = w, w+4, ...
    const float scale = 0.17677669529663689f;
    for (int pos = w; pos < 25; pos += 4) {
        const int hp = (ly + pos / 5) * 12 + lx + pos % 5;
        const _Float16* kr = sK + hp * 40;
        h2 kreg[16];
        #pragma unroll
        for (int j = 0; j < 4; j++)
            *(uint4*)(&kreg[j * 4]) = *(const uint4*)(kr + j * 8);
        float s0 = 0.f, s1 = 0.f;
        #pragma unroll
        for (int j = 0; j < 8; j++) {
            s0 = dot2acc(qreg[2 * j], kreg[2 * j], s0);
            s1 = dot2acc(qreg[2 * j + 1], kreg[2 * j + 1], s1);
        }
        sS[px * 28 + pos] = (s0 + s1) * scale;
    }
    __syncthreads();

    // softmax over 25 positions (one thread per pixel)
    if (t < 64) {
        float* row = sS + t * 28;
        float m = row[0];
        #pragma unroll
        for (int p = 1; p < 25; p++) m = fmaxf(m, row[p]);
        float sum = 0.f;
        float e[25];
        #pragma unroll
        for (int p = 0; p < 25; p++) { e[p] = __expf(row[p] - m); sum += e[p]; }
        const float inv = 1.f / sum;
        #pragma unroll
        for (int p = 0; p < 25; p++) row[p] = e[p] * inv;
    }
    __syncthreads();

    // PV: wave w handles d in [w*8, w*8+8)
    float at[25];
    #pragma unroll
    for (int p = 0; p < 25; p++) at[p] = sS[px * 28 + p];

    float f[8];
    #pragma unroll
    for (int j = 0; j < 8; j++) f[j] = 0.f;
    for (int p = 0; p < 25; p++) {
        const int hp = (ly + p / 5) * 12 + lx + p % 5;
        h2 vreg[4];
        *(uint4*)vreg = *(const uint4*)(sV + hp * 40 + w * 8);
        #pragma unroll
        for (int j = 0; j < 4; j++) {
            f[2 * j]     += at[p] * (float)vreg[j][0];
            f[2 * j + 1] += at[p] * (float)vreg[j][1];
        }
    }
    _Float16 ho[8];
    #pragma unroll
    for (int j = 0; j < 8; j++) ho[j] = (_Float16)f[j];
    *(uint4*)(ao + ((size_t)b * PP + gp) * 128 + h * 32 + w * 8) = *(uint4*)ho;
}

// ---------------------------------------------------------------------------
// Proj GEMM: out[b][c][p] = sum_o wproj[c][o] * ao[b][p][o], fp32 out.
// Block: 64px x 128c. Wave: 32px x 64c.
// ---------------------------------------------------------------------------
__global__ __launch_bounds__(256) void proj_gemm(
    const _Float16* __restrict__ ao, const _Float16* __restrict__ wproj,
    float* __restrict__ out)
{
    const int b = blockIdx.z;
    const int p0 = blockIdx.x * 64;
    const int t = threadIdx.x;
    const int w = t >> 6, lane = t & 63;
    const int lm = lane & 15, quad = lane >> 4;
    const int ms0 = (w & 1) * 32;
    const int nw = (w >> 1) * 64;

    const _Float16* ab = ao + (size_t)b * PP * 128;
    float* ob = out + (size_t)b * 128 * PP;

    f16x8 A[2][4];
    #pragma unroll
    for (int ms = 0; ms < 2; ms++)
        #pragma unroll
        for (int kc = 0; kc < 4; kc++)
            A[ms][kc] = *(const f16x8*)(ab + (size_t)(p0 + ms0 + ms * 16 + lm) * 128
                                        + kc * 32 + quad * 8);

    for (int nt = 0; nt < 4; nt++) {
        const int n0 = nw + nt * 16;
        f16x8 Bf[4];
        #pragma unroll
        for (int kc = 0; kc < 4; kc++)
            Bf[kc] = *(const f16x8*)(wproj + (size_t)(n0 + lm) * 128 + kc * 32 + quad * 8);
        f32x4 acc[2];
        #pragma unroll
        for (int ms = 0; ms < 2; ms++) {
            acc[ms] = (f32x4){0.f, 0.f, 0.f, 0.f};
            #pragma unroll
            for (int kc = 0; kc < 4; kc++)
                acc[ms] = __builtin_amdgcn_mfma_f32_16x16x32_f16(A[ms][kc], Bf[kc], acc[ms], 0, 0, 0);
        }
        #pragma unroll
        for (int ms = 0; ms < 2; ms++) {
            float4 v = make_float4(acc[ms][0], acc[ms][1], acc[ms][2], acc[ms][3]);
            *(float4*)(ob + (size_t)(n0 + lm) * PP + p0 + ms0 + ms * 16 + quad * 4) = v;
        }
    }
}

extern "C" void kernel_launch(void* const* d_in, const int* in_sizes, int n_in,
                              void* d_out, int out_size, void* d_ws, size_t ws_size,
                              hipStream_t stream)
{
    const float* x  = (const float*)d_in[0];
    const float* wq = (const float*)d_in[1];
    const float* wk = (const float*)d_in[2];
    const float* wv = (const float*)d_in[3];
    const float* wp = (const float*)d_in[4];
    float* out = (float*)d_out;

    _Float16* ws    = (_Float16*)d_ws;
    _Float16* xT    = ws;                       // 2*9216*128
    _Float16* wqkv  = xT + 2359296;             // 384*128
    _Float16* wproj = wqkv + 49152;             // 128*128
    _Float16* qkvh  = wproj + 16384;            // 2*9216*384
    _Float16* aoh   = qkvh + 7077888;           // 2*9216*128

    prep<<<dim3(288, 5, 2), 256, 0, stream>>>(x, wq, wk, wv, wp, xT, wqkv, wproj);
    qkv_gemm<<<dim3(144, 2, 2), 256, 0, stream>>>(xT, wqkv, qkvh);
    attn2<<<dim3(12, 12, 8), 256, 0, stream>>>(qkvh, aoh);
    proj_gemm<<<dim3(144, 1, 2), 256, 0, stream>>>(aoh, wproj, out);
}